// Round 7
// baseline (182.818 us; speedup 1.0000x reference)
//
#include <hip/hip_runtime.h>

// EdgeConv, algebraically simplified:
//   out[p,o] = sum_c (t[p,c]/K - x[p,c])*W[o,c] + sum_c x[p,c]*W[o,64+c] + b[o]
//   t[p,c]   = sum_{k=0..19} g_flat[p, 20c+k],  g_flat[p,j] = x[b, adj[p,j>>6], j&63]
// R6: width-16 global_load_lds (4 rows/inst -> 6 vmem/point instead of 21,
//     ~4x less DMA address VALU); f32 fbuf + inline cvt (removes R5's two
//     LDS round-trips from the serial chain); WPB=2 + no W LDS stage ->
//     22.5 KB/block -> 7 blocks/CU (14 waves, was 12).

typedef __fp16 half2_t __attribute__((ext_vector_type(2)));
typedef unsigned int u32;

#if __has_builtin(__builtin_amdgcn_fdot2)
#define FDOT2(a, b, c) __builtin_amdgcn_fdot2((a), (b), (c), false)
#else
#define FDOT2(a, b, c) fmaf((float)((a)[0]), (float)((b)[0]), fmaf((float)((a)[1]), (float)((b)[1]), (c)))
#endif

namespace {
constexpr int N_    = 32768;
constexpr int K_    = 20;
constexpr int C_    = 64;
constexpr int O_    = 64;
constexpr int BLOCK = 128;                 // 2 waves
constexpr int WPB   = 2;
constexpr int GRID  = 1792;                // persistent: exactly 7 blocks/CU
constexpr int ROWS  = K_ + 1;              // 20 neighbor rows + center row
constexpr int WBUF  = ROWS * C_;           // 1344 floats per stage buffer
constexpr int WAVES_PER_BATCH = (GRID / 8) * 2 * WPB;   // 896
}

__global__ __launch_bounds__(BLOCK, 3) void edgeconv_kernel(
    const float* __restrict__ x,     // (B,N,C)
    const int*   __restrict__ adj,   // (B,N,K)
    const float* __restrict__ W,     // (O, 2C)
    const float* __restrict__ bias,  // (O,)
    float*       __restrict__ out)   // (B,N,O)
{
  __shared__ __align__(16) float win2[WPB][2][WBUF];   // 21504 B
  __shared__ __align__(16) float fbuf[WPB][2 * C_];    //  1024 B -> 22528 total

  const int lane = threadIdx.x & 63;
  const int wid  = __builtin_amdgcn_readfirstlane((int)(threadIdx.x >> 6));
  const int sub  = lane & 15;                          // lane within row-quad

  // ---- prologue: lane o reads W[o][0..127] straight from global (one-time,
  // L2-served; chunked with compiler barriers so <=32 loads are in flight)
  half2_t wp[64];
  {
    const float2* wr = reinterpret_cast<const float2*>(W + lane * 2 * C_);
#pragma unroll
    for (int ch = 0; ch < 4; ++ch) {
#pragma unroll
      for (int i = 0; i < 16; ++i) {                   // constant idx -> regs
        const float2 f = wr[ch * 16 + i];
        wp[ch * 16 + i] = __builtin_amdgcn_cvt_pkrtz(f.x, f.y);
      }
      asm volatile("" ::: "memory");                   // bound load batching
    }
  }
  const float bl = bias[lane];

  // XCD<->batch partition: blockIdx%8 -> XCD; one batch per 2 XCD slots.
  const int xslot = blockIdx.x & 7;
  const int batch = xslot >> 1;                                // 0..3
  const int group = ((blockIdx.x >> 3) << 1) | (xslot & 1);    // 0..447
  const int wv    = group * WPB + wid;                         // 0..895 in batch
  const int cnt   = (N_ - wv + WAVES_PER_BATCH - 1) / WAVES_PER_BATCH; // 36/37
  const float* xb   = x + (size_t)batch * (N_ * C_);
  const int*   adjb = adj + (size_t)batch * N_ * K_;

  const bool b16 = (lane & 16) != 0;
  const bool b32m = (lane & 32) != 0;

  int idx[K_];                      // wave-uniform -> SGPRs

  auto loadidx = [&](int n) {
    const int* ar = adjb + n * K_;                     // uniform -> s_load
#pragma unroll
    for (int k = 0; k < K_; ++k) idx[k] = ar[k];
  };
  auto issue = [&](int n, int bsel) {
    auto ldsw = (__attribute__((address_space(3))) u32*)(&win2[wid][bsel][0]);
#pragma unroll
    for (int g = 0; g < 5; ++g) {
      // per-lane row: quad q=lane>>4 takes neighbor 4g+q (3 cndmask)
      const int lo  = b16 ? idx[4 * g + 1] : idx[4 * g + 0];
      const int hi  = b16 ? idx[4 * g + 3] : idx[4 * g + 2];
      const int row = b32m ? hi : lo;
      const float* src = xb + row * C_ + sub * 4;      // 16B per lane
      __builtin_amdgcn_global_load_lds(
          (const __attribute__((address_space(1))) u32*)src,
          ldsw + g * 256, 16, 0, 0);                   // 4 rows = 1024 B
    }
    const float* srcx = xb + n * C_ + lane;            // center row -> row 20
    __builtin_amdgcn_global_load_lds(
        (const __attribute__((address_space(1))) u32*)srcx,
        ldsw + K_ * C_, 4, 0, 0);
  };

  loadidx(wv);
  issue(wv, 0);
  if (cnt > 1) loadidx(wv + WAVES_PER_BATCH);

  for (int it = 0; it < cnt; ++it) {
    const int n   = wv + it * WAVES_PER_BATCH;
    const int cur = it & 1;

    if (it + 1 < cnt) {
      issue(n + WAVES_PER_BATCH, cur ^ 1);
      // drain everything older than [6 new DMAs + store(it-1)] = point it ready
      if (it == 0) asm volatile("s_waitcnt vmcnt(6)" ::: "memory");
      else         asm volatile("s_waitcnt vmcnt(7)" ::: "memory");
    } else {
      asm volatile("s_waitcnt vmcnt(1)" ::: "memory"); // only store(it-1) newer
    }
    __builtin_amdgcn_wave_barrier();

    if (it + 2 < cnt) loadidx(wv + (it + 2) * WAVES_PER_BATCH);

    // window sum: lane c reads flat[20c..20c+19] as 5x float4 (16B aligned)
    const float* mywin = &win2[wid][cur][0];
    const float4* wq = reinterpret_cast<const float4*>(mywin + lane * K_);
    const float4 v0 = wq[0], v1 = wq[1], v2 = wq[2], v3 = wq[3], v4 = wq[4];
    const float s0 = (v0.x + v0.y) + (v0.z + v0.w);
    const float s1 = (v1.x + v1.y) + (v1.z + v1.w);
    const float s2 = (v2.x + v2.y) + (v2.z + v2.w);
    const float s3 = (v3.x + v3.y) + (v3.z + v3.w);
    const float s4 = (v4.x + v4.y) + (v4.z + v4.w);
    const float t  = ((s0 + s1) + (s2 + s3)) + s4;
    const float xv = mywin[K_ * C_ + lane];

    fbuf[wid][lane]      = t * (1.f / K_) - xv;        // a[c]
    fbuf[wid][C_ + lane] = xv;                         // x[c]
    asm volatile("s_waitcnt lgkmcnt(0)" ::: "memory");
    __builtin_amdgcn_wave_barrier();

    // matvec: 32 broadcast ds_read_b128 + 64 cvt + 64 fdot2, 4 acc chains
    float acc0 = 0.f, acc1 = 0.f, acc2 = 0.f, acc3 = 0.f;
    const float4* bp = reinterpret_cast<const float4*>(fbuf[wid]);
#pragma unroll
    for (int i = 0; i < 16; ++i) {
      const float4 va = bp[i];
      const float4 vb = bp[i + 16];
      acc0 = FDOT2(__builtin_amdgcn_cvt_pkrtz(va.x, va.y), wp[2 * i + 0], acc0);
      acc1 = FDOT2(__builtin_amdgcn_cvt_pkrtz(va.z, va.w), wp[2 * i + 1], acc1);
      acc2 = FDOT2(__builtin_amdgcn_cvt_pkrtz(vb.x, vb.y), wp[32 + 2 * i], acc2);
      acc3 = FDOT2(__builtin_amdgcn_cvt_pkrtz(vb.z, vb.w), wp[33 + 2 * i], acc3);
    }

    out[((size_t)batch * N_ + n) * O_ + lane] = ((acc0 + acc1) + (acc2 + acc3)) + bl;
  }
}

extern "C" void kernel_launch(void* const* d_in, const int* in_sizes, int n_in,
                              void* d_out, int out_size, void* d_ws, size_t ws_size,
                              hipStream_t stream) {
  const float* x    = (const float*)d_in[0];
  const int*   adj  = (const int*)d_in[1];
  const float* W    = (const float*)d_in[2];
  const float* bias = (const float*)d_in[3];
  float* out = (float*)d_out;

  hipLaunchKernelGGL(edgeconv_kernel, dim3(GRID), dim3(BLOCK), 0, stream,
                     x, adj, W, bias, out);
}

// Round 8
// 158.111 us; speedup vs baseline: 1.1563x; 1.1563x over previous
//
#include <hip/hip_runtime.h>

// EdgeConv, algebraically simplified:
//   out[p,o] = sum_c t[p,c]*(W[o,c]/K) + sum_c x[p,c]*(W[o,64+c]-W[o,c]) + b[o]
//   t[p,c]   = sum_{k=0..19} g_flat[p, 20c+k]  (raw window sums of flat gather)
// R7: phase-0 f32->f16 conversion of x into d_ws (4 MB/batch -> fits one XCD
//     L2 -> gather becomes L2-resident); 3 width-16 DMAs/point (8 rows/instr,
//     center folded in); window sum via fdot2(ones); /K and concat-subtract
//     folded into W in prologue; f16 pack via 4 shfl (no LDS bounce);
//     coalesced two-pass LDS-staged W prologue (R6's strided W fill was the
//     ~25us regression).

typedef __fp16 half2_t __attribute__((ext_vector_type(2)));
typedef unsigned int u32;
typedef unsigned short u16;
#define AS1 __attribute__((address_space(1)))
#define AS3 __attribute__((address_space(3)))

#if __has_builtin(__builtin_amdgcn_fdot2)
#define FDOT2(a, b, c) __builtin_amdgcn_fdot2((a), (b), (c), false)
#else
#define FDOT2(a, b, c) fmaf((float)((a)[0]), (float)((b)[0]), fmaf((float)((a)[1]), (float)((b)[1]), (c)))
#endif

namespace {
constexpr int N_    = 32768;
constexpr int C_    = 64;
constexpr int O_    = 64;
constexpr int BLOCK = 256;                 // 4 waves
constexpr int WPB   = 4;
constexpr int GRID  = 2048;                // 512 blocks/batch; 16 pts/wave exact
constexpr int STEP  = 2048;                // waves per batch
constexpr int CNT   = 16;                  // N_/STEP, uniform for all waves
constexpr int WROWU = 24 * C_ / 2;         // 768 u32 per window buffer (24 rows x 128B)
}

__global__ void convert_kernel(const float* __restrict__ x, u32* __restrict__ ws) {
  const int total = 4 * N_ * C_ / 2;       // f16-pair count
  int i = blockIdx.x * blockDim.x + threadIdx.x;
  for (; i < total; i += gridDim.x * blockDim.x) {
    const float2 f = reinterpret_cast<const float2*>(x)[i];
    ws[i] = __builtin_bit_cast(u32, __builtin_amdgcn_cvt_pkrtz(f.x, f.y));
  }
}

__global__ __launch_bounds__(BLOCK, 4) void edgeconv_kernel(
    const u32*   __restrict__ xh,    // (B,N,32) u32 = f16 pairs (from phase 0)
    const int*   __restrict__ adj,   // (B,N,K)
    const float* __restrict__ W,     // (O, 2C)
    const float* __restrict__ bias,  // (O,)
    float*       __restrict__ out)   // (B,N,O)
{
  __shared__ __align__(16) u32 smem[WPB * 2 * WROWU + WPB * C_];  // 25600 B

  const int lane = threadIdx.x & 63;
  const int wid  = __builtin_amdgcn_readfirstlane((int)(threadIdx.x >> 6));

  // ---- prologue: two-pass coalesced W stage -> folded wp[64] f16 pairs.
  // wp[j<32]  = (W1[2j],W1[2j+1]) / 20       (t-part)
  // wp[j>=32] = (W2[..]-W1[..])              (x-part)
  half2_t wp[64];
  {
    float* stage = reinterpret_cast<float*>(smem);   // 32 rows x 132 floats
    for (int pass = 0; pass < 2; ++pass) {
      for (int i = threadIdx.x; i < 32 * 128; i += BLOCK)
        stage[(i >> 7) * 132 + (i & 127)] = W[(pass * 32 + (i >> 7)) * 128 + (i & 127)];
      __syncthreads();
      if ((lane >> 5) == pass) {
        const float2* wr = reinterpret_cast<const float2*>(stage + (lane & 31) * 132);
#pragma unroll
        for (int j = 0; j < 32; ++j) {
          const float2 f1 = wr[j], f2 = wr[j + 32];
          wp[j]      = __builtin_amdgcn_cvt_pkrtz(f1.x * 0.05f, f1.y * 0.05f);
          wp[j + 32] = __builtin_amdgcn_cvt_pkrtz(f2.x - f1.x, f2.y - f1.y);
        }
      }
      __syncthreads();
    }
  }
  const float bl = bias[lane];
  const int  s0 = (2 * lane) & 63, s1 = (2 * lane + 1) & 63;
  const bool lowhalf = lane < 32;
  const half2_t ones = __builtin_bit_cast(half2_t, (u32)0x3C003C00);

  u32* winbase = smem + wid * 2 * WROWU;
  u32* myhb    = smem + WPB * 2 * WROWU + wid * C_;

  // XCD<->batch partition: blockIdx%8 -> XCD; one batch per 2 XCD slots.
  const int xslot = blockIdx.x & 7;
  const int batch = xslot >> 1;                                // 0..3
  const int group = ((blockIdx.x >> 3) << 1) | (xslot & 1);    // 0..511
  const int wv0   = group * WPB + wid;                         // 0..2047
  const u32* xb16 = xh + (size_t)batch * N_ * 32;              // 128 B rows
  const int* adjb = adj + (size_t)batch * N_ * 20;

  int idx[20];                                                 // wave-uniform

  auto loadidx = [&](int n) {
    const int* ar = adjb + n * 20;
#pragma unroll
    for (int k = 0; k < 20; ++k) idx[k] = ar[k];
  };
  auto issue = [&](int n, int bsel) {
    AS3 u32* lds = (AS3 u32*)(winbase + bsel * WROWU);
    const int co = (lane & 7) << 2;                            // 16B chunk in row
    {  // rows 0..7 = idx[0..7]
      const int a01 = (lane & 8) ? idx[1] : idx[0], a23 = (lane & 8) ? idx[3] : idx[2];
      const int a45 = (lane & 8) ? idx[5] : idx[4], a67 = (lane & 8) ? idx[7] : idx[6];
      const int b0 = (lane & 16) ? a23 : a01, b1 = (lane & 16) ? a67 : a45;
      const int row = (lane & 32) ? b1 : b0;
      __builtin_amdgcn_global_load_lds((const AS1 u32*)(xb16 + ((size_t)row << 5) + co),
                                       lds, 16, 0, 0);
    }
    {  // rows 8..15 = idx[8..15]
      const int a01 = (lane & 8) ? idx[9] : idx[8],  a23 = (lane & 8) ? idx[11] : idx[10];
      const int a45 = (lane & 8) ? idx[13] : idx[12], a67 = (lane & 8) ? idx[15] : idx[14];
      const int b0 = (lane & 16) ? a23 : a01, b1 = (lane & 16) ? a67 : a45;
      const int row = (lane & 32) ? b1 : b0;
      __builtin_amdgcn_global_load_lds((const AS1 u32*)(xb16 + ((size_t)row << 5) + co),
                                       lds + 256, 16, 0, 0);
    }
    {  // rows 16..19 = idx[16..19]; rows 20..23 = center (row 20 used for xv)
      const int a01 = (lane & 8) ? idx[17] : idx[16], a23 = (lane & 8) ? idx[19] : idx[18];
      const int b0 = (lane & 16) ? a23 : a01;
      const int row = (lane & 32) ? n : b0;
      __builtin_amdgcn_global_load_lds((const AS1 u32*)(xb16 + ((size_t)row << 5) + co),
                                       lds + 512, 16, 0, 0);
    }
  };

  loadidx(wv0);
  issue(wv0, 0);
  loadidx(wv0 + STEP);

  for (int it = 0; it < CNT; ++it) {
    const int n   = wv0 + it * STEP;
    const int cur = it & 1;

    if (it + 1 < CNT) {
      issue(n + STEP, cur ^ 1);
      asm volatile("s_waitcnt vmcnt(3)" ::: "memory");   // newest 3 = next group
    } else {
      asm volatile("s_waitcnt vmcnt(1)" ::: "memory");   // newest 1 = last store
    }
    __builtin_amdgcn_wave_barrier();

    if (it + 2 < CNT) loadidx(wv0 + (it + 2) * STEP);

    // window sum: lane c's 20 f16 at bytes 40c..40c+39 -> 5 x b64, fdot2(ones)
    const u32* mywin = winbase + cur * WROWU;
    const uint2* myq = reinterpret_cast<const uint2*>(mywin) + 5 * lane;
    float tA = 0.f, tB = 0.f;
#pragma unroll
    for (int s = 0; s < 5; ++s) {
      const uint2 d = myq[s];
      tA = FDOT2(__builtin_bit_cast(half2_t, d.x), ones, tA);
      tB = FDOT2(__builtin_bit_cast(half2_t, d.y), ones, tB);
    }
    const float t = tA + tB;                               // raw sum (K folded in W)
    const u16 hv = reinterpret_cast<const u16*>(mywin)[20 * C_ + lane];
    const float xv = (float)__builtin_bit_cast(__fp16, hv);

    // pack e = [t(0..63), x(0..63)] to f16 pairs via shfl (lane l -> e[2l],e[2l+1])
    const float tlo = __shfl(t, s0),  thi = __shfl(t, s1);
    const float xlo = __shfl(xv, s0), xhi = __shfl(xv, s1);
    const float lo = lowhalf ? tlo : xlo, hi = lowhalf ? thi : xhi;
    myhb[lane] = __builtin_bit_cast(u32, __builtin_amdgcn_cvt_pkrtz(lo, hi));
    asm volatile("s_waitcnt lgkmcnt(0)" ::: "memory");
    __builtin_amdgcn_wave_barrier();

    // matvec: 16 broadcast ds_read_b128 + 64 fdot2
    float acc0 = 0.f, acc1 = 0.f, acc2 = 0.f, acc3 = 0.f;
    const uint4* hb = reinterpret_cast<const uint4*>(myhb);
#pragma unroll
    for (int i = 0; i < 16; ++i) {
      const uint4 q = hb[i];
      acc0 = FDOT2(__builtin_bit_cast(half2_t, q.x), wp[4 * i + 0], acc0);
      acc1 = FDOT2(__builtin_bit_cast(half2_t, q.y), wp[4 * i + 1], acc1);
      acc2 = FDOT2(__builtin_bit_cast(half2_t, q.z), wp[4 * i + 2], acc2);
      acc3 = FDOT2(__builtin_bit_cast(half2_t, q.w), wp[4 * i + 3], acc3);
    }

    out[((size_t)batch * N_ + n) * O_ + lane] = ((acc0 + acc1) + (acc2 + acc3)) + bl;
  }
}

extern "C" void kernel_launch(void* const* d_in, const int* in_sizes, int n_in,
                              void* d_out, int out_size, void* d_ws, size_t ws_size,
                              hipStream_t stream) {
  const float* x    = (const float*)d_in[0];
  const int*   adj  = (const int*)d_in[1];
  const float* W    = (const float*)d_in[2];
  const float* bias = (const float*)d_in[3];
  float* out = (float*)d_out;
  u32*   ws  = (u32*)d_ws;                 // 16.8 MB f16 copy of x

  hipLaunchKernelGGL(convert_kernel, dim3(2048), dim3(BLOCK), 0, stream, x, ws);
  hipLaunchKernelGGL(edgeconv_kernel, dim3(GRID), dim3(BLOCK), 0, stream,
                     ws, adj, W, bias, out);
}